// Round 1
// 319.244 us; speedup vs baseline: 1.0116x; 1.0116x over previous
//
#include <hip/hip_runtime.h>
#include <cmath>

#define B_ROWS 16384
#define E_DIM 512
#define H_DIM 1024
#define P_DIM 256
#define K1_RAW 1026
#define K1_PAD 1152   // multiple of 128 -> even number of 64-K tiles for 8-phase GEMM

#define NEG_BIG (-3.0e38f)
#define SCL_IN  16.0f            // fp8 pre-scale for A1 and all weights
#define INV_G1  (1.0f / 256.0f)  // GEMM1: A(x16) * W(x16)
#define INV_G   (1.0f / 16.0f)   // GEMM2-4: A(x1) * W(x16)

typedef __attribute__((ext_vector_type(4))) short short4v;
typedef __attribute__((ext_vector_type(8))) short short8v;
typedef __attribute__((ext_vector_type(4))) float f32x4;
typedef __attribute__((ext_vector_type(2))) long long2v;

__device__ __forceinline__ short f2bf(float f) {
    unsigned u = __float_as_uint(f);
    u += 0x7fffu + ((u >> 16) & 1u);   // round-to-nearest-even
    return (short)(u >> 16);
}
__device__ __forceinline__ float bf2f(short s) {
    return __uint_as_float(((unsigned)(unsigned short)s) << 16);
}
// pack 4 floats -> 4 OCP e4m3 bytes (HW cvt, RNE+sat)
__device__ __forceinline__ int pk4_fp8(float a, float b, float c, float d) {
    int v = __builtin_amdgcn_cvt_pk_fp8_f32(a, b, 0, false);
    return  __builtin_amdgcn_cvt_pk_fp8_f32(c, d, v, true);
}

// K-interleave permutation: within each 64-k block, store the 8 eight-byte
// MFMA quad-chunks as [A0 B0 A1 B1 A2 B2 A3 B3] so one b128 read at quad*16
// returns {k-step0 frag, k-step1 frag} for mfma_16x16x32_fp8_fp8.
__device__ __forceinline__ int kperm(int k) {
    return (k & ~63) | (((k >> 3) & 3) << 4) | (((k >> 5) & 1) << 3) | (k & 7);
}

// async global->LDS DMA, 16 B/lane; lds dest = wave-uniform base + lane*16
__device__ __forceinline__ void g2lds16(const void* g, void* l) {
    __builtin_amdgcn_global_load_lds(
        (const __attribute__((address_space(1))) void*)g,
        (__attribute__((address_space(3))) void*)l, 16, 0, 0);
}

// ---------------------------------------------------------------------------
// prep_a1: per-row L2 norms + emit fp8 A1[b][1152] (K-interleaved).
// Single global read: thread t's reduction float4 IS the data it quantizes.
__global__ __launch_bounds__(256) void prep_a1(
    const float* __restrict__ x1, const float* __restrict__ x2,
    const float* __restrict__ gf, char* __restrict__ A1)
{
    const int b = blockIdx.x;
    const int t = threadIdx.x;
    __shared__ float red[4];

    const float* src = (t < 128) ? x1 : x2;
    const int idx = (t & 127) << 2;
    float4 v = *(const float4*)&src[(size_t)b * E_DIM + idx];
    float ss = v.x*v.x + v.y*v.y + v.z*v.z + v.w*v.w;
    #pragma unroll
    for (int off = 32; off > 0; off >>= 1) ss += __shfl_xor(ss, off, 64);
    if ((t & 63) == 0) red[t >> 6] = ss;
    __syncthreads();
    const float inv1 = SCL_IN / fmaxf(sqrtf(red[0] + red[1]), 1e-12f);
    const float inv2 = SCL_IN / fmaxf(sqrtf(red[2] + red[3]), 1e-12f);
    const float iv = (t < 128) ? inv1 : inv2;

    const size_t rb = (size_t)b * K1_PAD;
    // k = t*4: t<128 covers x1 floats 0..511, t>=128 covers x2 -> k 512..1023
    *(int*)&A1[rb + kperm(t << 2)] = pk4_fp8(v.x * iv, v.y * iv, v.z * iv, v.w * iv);
    if (t < 32) {
        const int k = 1024 + (t << 2);   // covers full pad block 1024..1151
        float vals[4];
        #pragma unroll
        for (int i = 0; i < 4; ++i) {
            int kk = k + i;
            vals[i] = (kk == 1024) ? gf[(size_t)b * 2 + 0] * SCL_IN
                    : (kk == 1025) ? gf[(size_t)b * 2 + 1] * SCL_IN : 0.f;
        }
        *(int*)&A1[rb + kperm(k)] = pk4_fp8(vals[0], vals[1], vals[2], vals[3]);
    }
}

// ---------------------------------------------------------------------------
// transpose_cvt_all: W fp32 [K][N] -> Wt fp8 [N][Kpad] (K-interleaved, x16).
__global__ __launch_bounds__(256) void transpose_cvt_all(
    const float* __restrict__ W0, char* __restrict__ Wt0,
    const float* __restrict__ W1, char* __restrict__ Wt1,
    const float* __restrict__ W2, char* __restrict__ Wt2,
    const float* __restrict__ W3, char* __restrict__ Wt3)
{
    const int z = blockIdx.z;
    const float* W; char* Wt; int K, N, Kpad;
    if (z == 0)      { W = W0; Wt = Wt0; K = K1_RAW; N = H_DIM; Kpad = K1_PAD; }
    else if (z == 1) { W = W1; Wt = Wt1; K = H_DIM;  N = H_DIM; Kpad = H_DIM; }
    else if (z == 2) { W = W2; Wt = Wt2; K = H_DIM;  N = H_DIM; Kpad = H_DIM; }
    else             { W = W3; Wt = Wt3; K = H_DIM;  N = P_DIM; Kpad = H_DIM; }

    const int k0 = blockIdx.x * 64, n0 = blockIdx.y * 64;
    if (k0 >= Kpad || n0 >= N) return;

    __shared__ float T[64][68];
    const int t = threadIdx.x;
    const int r = t >> 4;          // 0..15
    const int c = (t & 15) << 2;   // 0..60
    #pragma unroll
    for (int rr = 0; rr < 4; ++rr) {
        int k = k0 + r + rr * 16;
        float4 v = (k < K) ? *(const float4*)&W[(size_t)k * N + n0 + c]
                           : make_float4(0.f, 0.f, 0.f, 0.f);
        v.x *= SCL_IN; v.y *= SCL_IN; v.z *= SCL_IN; v.w *= SCL_IN;
        *(float4*)&T[r + rr * 16][c] = v;
    }
    __syncthreads();
    const int n = n0 + (t >> 2);
    const int cn = t >> 2;
    const int ks = (t & 3) << 4;   // 0,16,32,48
    #pragma unroll
    for (int g = 0; g < 2; ++g) {
        int kk = ks + g * 8;
        int k = k0 + kk;
        if (k + 7 < Kpad) {
            int lo = pk4_fp8(T[kk+0][cn], T[kk+1][cn], T[kk+2][cn], T[kk+3][cn]);
            int hi = pk4_fp8(T[kk+4][cn], T[kk+5][cn], T[kk+6][cn], T[kk+7][cn]);
            int2 o = { lo, hi };
            int np = k0 + (((kk >> 3) & 3) << 4) + (((kk >> 5) & 1) << 3);
            *(int2*)&Wt[(size_t)n * Kpad + np] = o;
        }
    }
}

// ---------------------------------------------------------------------------
// gemm256_f8: 256x256-tile 8-phase fp8 GEMM (T3+T4 counted vmcnt + T5 setprio).
// 512 thr = 8 waves (2M x 4N), wave tile 128x64, BK=64, double-buffered LDS
// (slot0 = even K-tiles, slot1 = odd). Per phase: frag ds_reads + exactly one
// 8KB half-tile global_load_lds + barrier + 16 MFMA + barrier. vmcnt(2) only
// at phases 4 and 8 (loads stay in flight across barriers, never drained to 0
// in the main loop). Chunk-issue plan (iter j, t0=2j, t1=2j+1):
//   ph1: B-lo(t1)->sB1   ph2: B-hi(t1)->sB1   ph3: A-lo(t0+2)->sA0
//   ph4: A-hi(t0+2)      ph5: B-lo(t0+2)->sB0 ph6: B-hi(t0+2)
//   ph7: A-lo(t1+2)->sA1 ph8: A-hi(t1+2)
// Every staged region is >=1 full barrier past its last ds_read consumer.
template <int KA>
__global__ __launch_bounds__(512, 2) void gemm256_f8(
    const char* __restrict__ A, const char* __restrict__ Bt,
    const float* __restrict__ bias, float cscale,
    short* __restrict__ Cb, int N)
{
    constexpr int NK = KA >> 6;      // 64-K tiles
    constexpr int NI = NK >> 1;      // iterations (2 tiles each)
    static_assert((NK & 1) == 0 && NK >= 4, "need even NK >= 4");
    constexpr int LDSZ = 128 * 264 * 2 > 65536 ? 128 * 264 * 2 : 65536;

    __shared__ __align__(16) char smem[LDSZ];

    const int t = threadIdx.x;
    const int w = t >> 6, lane = t & 63;
    const int wu = __builtin_amdgcn_readfirstlane(w);
    const int wm = w & 1, wn = w >> 1;
    const int m16 = lane & 15, quad = lane >> 4;
    const int row0 = blockIdx.x * 256, col0 = blockIdx.y * 256;

    // staging sources: wave w covers 16 rows of each 128-row half-tile
    const char* AgLo = A  + (size_t)(row0 + wu * 16 + (lane >> 2)) * KA + ((lane & 3) << 4);
    const char* AgHi = AgLo + (size_t)128 * KA;
    const char* BgLo = Bt + (size_t)(col0 + wu * 16 + (lane >> 2)) * KA + ((lane & 3) << 4);
    const char* BgHi = BgLo + (size_t)128 * KA;

    char* const sA0 = smem;              // [256][64] fp8, even tiles
    char* const sB0 = smem + 16384;
    char* const sA1 = smem + 32768;      // odd tiles
    char* const sB1 = smem + 49152;

    auto stage = [&](const char* g, size_t ko, char* l) {
        g2lds16(g + ko, l + (wu << 10));
    };

    f32x4 acc[8][4];
    #pragma unroll
    for (int i = 0; i < 8; ++i)
        #pragma unroll
        for (int j = 0; j < 4; ++j)
            acc[i][j] = (f32x4){0.f, 0.f, 0.f, 0.f};

    long2v a[8], b[4];

#define RD_A(SL, LO) do { _Pragma("unroll") for (int ii = 0; ii < 4; ++ii) \
    a[(LO)+ii] = *(const long2v*)&(SL)[(wm*128 + ((LO)+ii)*16 + m16)*64 + quad*16]; } while (0)
#define RD_B(SL, LO) do { _Pragma("unroll") for (int jj = 0; jj < 2; ++jj) \
    b[(LO)+jj] = *(const long2v*)&(SL)[(wn*64 + ((LO)+jj)*16 + m16)*64 + quad*16]; } while (0)
#define QMFMA(I0, J0) do { _Pragma("unroll") for (int ii = 0; ii < 4; ++ii) \
    { _Pragma("unroll") for (int jj = 0; jj < 2; ++jj) { \
        acc[(I0)+ii][(J0)+jj] = __builtin_amdgcn_mfma_f32_16x16x32_fp8_fp8( \
            a[(I0)+ii][0], b[(J0)+jj][0], acc[(I0)+ii][(J0)+jj], 0, 0, 0); \
        acc[(I0)+ii][(J0)+jj] = __builtin_amdgcn_mfma_f32_16x16x32_fp8_fp8( \
            a[(I0)+ii][1], b[(J0)+jj][1], acc[(I0)+ii][(J0)+jj], 0, 0, 0); \
    } } } while (0)
#define BAR  __builtin_amdgcn_s_barrier()
#define PRI1 __builtin_amdgcn_s_setprio(1)
#define PRI0 __builtin_amdgcn_s_setprio(0)

    // prologue: tile0 (A+B), tile1 (A only; its B arrives at iter0 ph1/ph2)
    stage(AgLo, 0, sA0);  stage(AgHi, 0, sA0 + 8192);
    stage(BgLo, 0, sB0);  stage(BgHi, 0, sB0 + 8192);
    stage(AgLo, 64, sA1); stage(AgHi, 64, sA1 + 8192);
    asm volatile("s_waitcnt vmcnt(2)" ::: "memory");   // tile0 resident
    BAR;

    #pragma unroll 1
    for (int it = 0; it < NI - 1; ++it) {
        const size_t kB1 = (size_t)(2 * it + 1) << 6;
        const size_t kA2 = (size_t)(2 * it + 2) << 6;
        const size_t kA3 = (size_t)(2 * it + 3) << 6;

        // ---- tile t0 (slot0) ----
        RD_A(sA0, 0); RD_B(sB0, 0);
        stage(BgLo, kB1, sB1);
        BAR; PRI1; QMFMA(0, 0); PRI0; BAR;

        RD_A(sA0, 4);
        stage(BgHi, kB1, sB1 + 8192);
        BAR; PRI1; QMFMA(4, 0); PRI0; BAR;

        RD_B(sB0, 2);
        stage(AgLo, kA2, sA0);
        BAR; PRI1; QMFMA(0, 2); PRI0; BAR;

        stage(AgHi, kA2, sA0 + 8192);
        asm volatile("s_waitcnt vmcnt(2)" ::: "memory");  // t1 fully resident
        BAR; PRI1; QMFMA(4, 2); PRI0; BAR;

        // ---- tile t1 (slot1) ----
        RD_A(sA1, 0); RD_B(sB1, 0);
        stage(BgLo, kA2, sB0);
        BAR; PRI1; QMFMA(0, 0); PRI0; BAR;

        RD_A(sA1, 4);
        stage(BgHi, kA2, sB0 + 8192);
        BAR; PRI1; QMFMA(4, 0); PRI0; BAR;

        RD_B(sB1, 2);
        stage(AgLo, kA3, sA1);
        BAR; PRI1; QMFMA(0, 2); PRI0; BAR;

        stage(AgHi, kA3, sA1 + 8192);
        asm volatile("s_waitcnt vmcnt(2)" ::: "memory");  // t0+2 fully resident
        BAR; PRI1; QMFMA(4, 2); PRI0; BAR;
    }

    // ---- peeled last iteration: only t1's B still needs staging ----
    {
        const size_t kB1 = (size_t)(NK - 1) << 6;

        RD_A(sA0, 0); RD_B(sB0, 0);
        stage(BgLo, kB1, sB1);
        BAR; PRI1; QMFMA(0, 0); PRI0; BAR;

        RD_A(sA0, 4);
        stage(BgHi, kB1, sB1 + 8192);
        BAR; PRI1; QMFMA(4, 0); PRI0; BAR;

        RD_B(sB0, 2);
        BAR; PRI1; QMFMA(0, 2); PRI0; BAR;

        asm volatile("s_waitcnt vmcnt(0)" ::: "memory");  // drain: t1 resident
        BAR; PRI1; QMFMA(4, 2); PRI0; BAR;

        RD_A(sA1, 0); RD_B(sB1, 0);
        BAR; PRI1; QMFMA(0, 0); PRI0; BAR;

        RD_A(sA1, 4);
        BAR; PRI1; QMFMA(4, 0); PRI0; BAR;

        RD_B(sB1, 2);
        BAR; PRI1; QMFMA(0, 2); PRI0; BAR;

        QMFMA(4, 2);
    }

    // ---- staged epilogue: 2 row-halves (by wm), coalesced short8 stores ----
    float bj[4];
    #pragma unroll
    for (int j = 0; j < 4; ++j)
        bj[j] = bias[col0 + wn * 64 + j * 16 + m16];

    short* Cs = (short*)smem;   // [128][264]
    #pragma unroll
    for (int ch = 0; ch < 2; ++ch) {
        __syncthreads();
        if (wm == ch) {
            #pragma unroll
            for (int i = 0; i < 8; ++i) {
                const int rbase = i * 16 + quad * 4;
                #pragma unroll
                for (int j = 0; j < 4; ++j) {
                    const int cc = wn * 64 + j * 16 + m16;
                    #pragma unroll
                    for (int r = 0; r < 4; ++r)
                        Cs[(rbase + r) * 264 + cc] = f2bf(acc[i][j][r] * cscale + bj[j]);
                }
            }
        }
        __syncthreads();
        #pragma unroll
        for (int p = 0; p < 8; ++p) {
            const int idx = p * 512 + t;
            const int r = idx >> 5, c8 = idx & 31;
            short8v v = *(const short8v*)&Cs[r * 264 + c8 * 8];
            *(short8v*)&Cb[(size_t)(row0 + ch * 128 + r) * N + col0 + c8 * 8] = v;
        }
    }
#undef RD_A
#undef RD_B
#undef QMFMA
#undef BAR
#undef PRI1
#undef PRI0
}

// ---------------------------------------------------------------------------
// gemm_f8 (legacy 2-phase 128-row tile) — kept for GEMM4 (N=256 needs the
// finer grid: 256 blocks vs 64 with the 256^2 tile).
template <int NWN, int KA>
__global__ __launch_bounds__(NWN * 128) void gemm_f8(
    const char* __restrict__ A, const char* __restrict__ Bt,
    const float* __restrict__ bias, float cscale,
    short* __restrict__ Cb, int N)
{
    constexpr int WAVES = 2 * NWN;
    constexpr int TN    = 64 * NWN;
    constexpr int NK    = KA >> 6;
    constexpr int A_PW  = 8 / WAVES;
    constexpr int B_PW  = (TN / 16) / WAVES;
    constexpr int KBUF  = (128 + TN) * 64;
    constexpr int STAGE = 128 * 132 * 2;
    constexpr int LDSZ  = (2 * KBUF > STAGE) ? 2 * KBUF : STAGE;

    __shared__ __align__(16) char smem[LDSZ];

    const int t = threadIdx.x;
    const int w = t >> 6, lane = t & 63;
    const int wm = w & 1, wn = w >> 1;
    const int m16 = lane & 15, quad = lane >> 4;
    const int row0 = blockIdx.x * 128, col0 = blockIdx.y * TN;

    const int wu = __builtin_amdgcn_readfirstlane(w);
    const char* Ag[A_PW];
    const char* Bg[B_PW];
    #pragma unroll
    for (int i = 0; i < A_PW; ++i) {
        int c = wu * A_PW + i;
        Ag[i] = A + (size_t)(row0 + c * 16 + (lane >> 2)) * KA + ((lane & 3) << 4);
    }
    #pragma unroll
    for (int i = 0; i < B_PW; ++i) {
        int c = wu * B_PW + i;
        Bg[i] = Bt + (size_t)(col0 + c * 16 + (lane >> 2)) * KA + ((lane & 3) << 4);
    }

    auto issue = [&](int kt, int bi) {
        char* As = smem + bi * KBUF;
        char* Bs = smem + bi * KBUF + 128 * 64;
        const size_t ko = (size_t)kt << 6;
        #pragma unroll
        for (int i = 0; i < A_PW; ++i)
            g2lds16(Ag[i] + ko, As + (wu * A_PW + i) * 1024);
        #pragma unroll
        for (int i = 0; i < B_PW; ++i)
            g2lds16(Bg[i] + ko, Bs + (wu * B_PW + i) * 1024);
    };

    f32x4 acc[4][4];
    #pragma unroll
    for (int i = 0; i < 4; ++i)
        #pragma unroll
        for (int j = 0; j < 4; ++j)
            acc[i][j] = (f32x4){0.f, 0.f, 0.f, 0.f};

    issue(0, 0);

    for (int kt = 0; kt < NK; ++kt) {
        asm volatile("s_waitcnt vmcnt(0)\n\ts_barrier" ::: "memory");
        if (kt + 1 < NK) issue(kt + 1, (kt + 1) & 1);

        const char* As = smem + (kt & 1) * KBUF;
        const char* Bs = smem + (kt & 1) * KBUF + 128 * 64;
        long2v a2[4], b2[4];
        #pragma unroll
        for (int i = 0; i < 4; ++i)
            a2[i] = *(const long2v*)&As[(wm * 64 + i * 16 + m16) * 64 + quad * 16];
        #pragma unroll
        for (int j = 0; j < 4; ++j)
            b2[j] = *(const long2v*)&Bs[(wn * 64 + j * 16 + m16) * 64 + quad * 16];
        #pragma unroll
        for (int i = 0; i < 4; ++i)
            #pragma unroll
            for (int j = 0; j < 4; ++j) {
                acc[i][j] = __builtin_amdgcn_mfma_f32_16x16x32_fp8_fp8(
                    a2[i][0], b2[j][0], acc[i][j], 0, 0, 0);
                acc[i][j] = __builtin_amdgcn_mfma_f32_16x16x32_fp8_fp8(
                    a2[i][1], b2[j][1], acc[i][j], 0, 0, 0);
            }
    }

    float bj[4];
    #pragma unroll
    for (int j = 0; j < 4; ++j)
        bj[j] = bias[col0 + wn * 64 + j * 16 + m16];

    short* Cs = (short*)smem;   // [128][132]
    #pragma unroll
    for (int ch = 0; ch < NWN / 2; ++ch) {
        __syncthreads();
        if ((wn >> 1) == ch) {
            const int colIn = (wn & 1) * 64;
            #pragma unroll
            for (int j = 0; j < 4; ++j) {
                const int cc = colIn + j * 16 + m16;
                #pragma unroll
                for (int i = 0; i < 4; ++i) {
                    const int rbase = wm * 64 + i * 16 + quad * 4;
                    #pragma unroll
                    for (int r = 0; r < 4; ++r)
                        Cs[(rbase + r) * 132 + cc] = f2bf(acc[i][j][r] * cscale + bj[j]);
                }
            }
        }
        __syncthreads();
        #pragma unroll
        for (int i = 0; i < 2048 / (NWN * 128); ++i) {
            const int idx = i * NWN * 128 + t;
            const int r = idx >> 4, c8 = idx & 15;
            short8v v = *(const short8v*)&Cs[r * 132 + c8 * 8];
            *(short8v*)&Cb[(size_t)(row0 + r) * N + col0 + ch * 128 + c8 * 8] = v;
        }
    }
}

// ---------------------------------------------------------------------------
// LN+ReLU, ONE WAVE PER ROW (4 rows/block, no barriers). bf16 in, fp8 out
// (K-interleaved) + optional bf16 running residual.
template <int HAS_RES, int WRITE_BF>
__global__ __launch_bounds__(256) void ln_relu_f8(
    const short* __restrict__ X, const float* __restrict__ gamma,
    const float* __restrict__ beta, const short* __restrict__ res,
    char* __restrict__ act, short* __restrict__ resout)
{
    const int row  = blockIdx.x * 4 + (threadIdx.x >> 6);
    const int lane = threadIdx.x & 63;
    const size_t base = (size_t)row * H_DIM;

    float y[4][4];
    float s = 0.f, ss = 0.f;
    #pragma unroll
    for (int j = 0; j < 4; ++j) {
        const int idx = j * 256 + lane * 4;
        short4v xb = *(const short4v*)&X[base + idx];
        #pragma unroll
        for (int e = 0; e < 4; ++e) {
            float xv = bf2f(xb[e]);
            y[j][e] = xv;
            s += xv; ss += xv * xv;
        }
    }
    #pragma unroll
    for (int off = 32; off > 0; off >>= 1) {
        s  += __shfl_xor(s,  off, 64);
        ss += __shfl_xor(ss, off, 64);
    }
    const float m = s * (1.f / H_DIM);
    const float var = fmaxf(ss * (1.f / H_DIM) - m * m, 0.f);
    const float r = 1.f / sqrtf(var + 1e-5f);

    #pragma unroll
    for (int j = 0; j < 4; ++j) {
        const int idx = j * 256 + lane * 4;
        float4 g  = *(const float4*)&gamma[idx];
        float4 be = *(const float4*)&beta[idx];
        float gv[4] = { g.x, g.y, g.z, g.w };
        float bv[4] = { be.x, be.y, be.z, be.w };
        #pragma unroll
        for (int e = 0; e < 4; ++e)
            y[j][e] = fmaxf((y[j][e] - m) * r * gv[e] + bv[e], 0.f);
        if (HAS_RES) {
            short4v rr = *(const short4v*)&res[base + idx];
            #pragma unroll
            for (int e = 0; e < 4; ++e) y[j][e] += bf2f(rr[e]);
        }
        *(int*)&act[base + kperm(idx)] = pk4_fp8(y[j][0], y[j][1], y[j][2], y[j][3]);
        if (WRITE_BF) {
            short4v o = { f2bf(y[j][0]), f2bf(y[j][1]), f2bf(y[j][2]), f2bf(y[j][3]) };
            *(short4v*)&resout[base + idx] = o;
        }
    }
}

// ---------------------------------------------------------------------------
// fused final LN (H=256, bf16 in) + classifier + gender mask.
__global__ __launch_bounds__(256) void ln_cls(
    const short* __restrict__ X, const float* __restrict__ gamma,
    const float* __restrict__ beta, const float* __restrict__ Wc,
    const float* __restrict__ bc, const float* __restrict__ gf,
    float* __restrict__ out)
{
    const int row  = blockIdx.x * 4 + (threadIdx.x >> 6);
    const int lane = threadIdx.x & 63;
    const size_t base = (size_t)row * P_DIM;
    const int k0 = lane * 4;

    short4v xb = *(const short4v*)&X[base + k0];
    float x[4];
    float s = 0.f, ss = 0.f;
    #pragma unroll
    for (int e = 0; e < 4; ++e) {
        x[e] = bf2f(xb[e]);
        s += x[e]; ss += x[e] * x[e];
    }
    #pragma unroll
    for (int off = 32; off > 0; off >>= 1) {
        s  += __shfl_xor(s,  off, 64);
        ss += __shfl_xor(ss, off, 64);
    }
    const float m = s * (1.f / P_DIM);
    const float var = fmaxf(ss * (1.f / P_DIM) - m * m, 0.f);
    const float r = 1.f / sqrtf(var + 1e-5f);

    float4 g  = *(const float4*)&gamma[k0];
    float4 be = *(const float4*)&beta[k0];
    float gv[4] = { g.x, g.y, g.z, g.w };
    float bv[4] = { be.x, be.y, be.z, be.w };
    float yv[4];
    #pragma unroll
    for (int e = 0; e < 4; ++e)
        yv[e] = fmaxf((x[e] - m) * r * gv[e] + bv[e], 0.f);

    float p[7] = {0.f, 0.f, 0.f, 0.f, 0.f, 0.f, 0.f};
    #pragma unroll
    for (int e = 0; e < 4; ++e) {
        const float* wr = &Wc[(k0 + e) * 7];
        #pragma unroll
        for (int c = 0; c < 7; ++c) p[c] += yv[e] * wr[c];
    }
    #pragma unroll
    for (int off = 32; off > 0; off >>= 1)
        #pragma unroll
        for (int c = 0; c < 7; ++c) p[c] += __shfl_xor(p[c], off, 64);

    if (lane == 0) {
        int g1 = (gf[(size_t)row * 2 + 0] != 0.f);
        int g2 = (gf[(size_t)row * 2 + 1] != 0.f);
        unsigned bits = (g1 == g2) ? (g1 ? 0x24u : 0x12u) : 0x49u;
        #pragma unroll
        for (int c = 0; c < 7; ++c)
            out[(size_t)row * 7 + c] = ((bits >> c) & 1u) ? p[c] + bc[c] : NEG_BIG;
    }
}

// ---------------------------------------------------------------------------
extern "C" void kernel_launch(void* const* d_in, const int* in_sizes, int n_in,
                              void* d_out, int out_size, void* d_ws, size_t ws_size,
                              hipStream_t stream)
{
    const float* x1   = (const float*)d_in[0];
    const float* x2   = (const float*)d_in[1];
    const float* gf   = (const float*)d_in[2];
    const float* W_in = (const float*)d_in[3];
    const float* b_in = (const float*)d_in[4];
    const float* g_in = (const float*)d_in[5];
    const float* be_in = (const float*)d_in[6];
    const float* W_r1 = (const float*)d_in[7];
    const float* b_r1 = (const float*)d_in[8];
    const float* g_r1 = (const float*)d_in[9];
    const float* be_r1 = (const float*)d_in[10];
    const float* W_r2 = (const float*)d_in[11];
    const float* b_r2 = (const float*)d_in[12];
    const float* g_r2 = (const float*)d_in[13];
    const float* be_r2 = (const float*)d_in[14];
    const float* W_f  = (const float*)d_in[15];
    const float* b_f  = (const float*)d_in[16];
    const float* g_f  = (const float*)d_in[17];
    const float* be_f = (const float*)d_in[18];
    const float* W_c  = (const float*)d_in[19];
    const float* b_c  = (const float*)d_in[20];
    float* out = (float*)d_out;

    const int B = B_ROWS;

    // ---- workspace layout ----
    char* p = (char*)d_ws;
    short* preb  = (short*)p;  p += (size_t)B * H_DIM * sizeof(float);   // bf16 GEMM out
    short* fb    = (short*)p;  p += (size_t)B * H_DIM * sizeof(short);   // bf16 running residual
    char*  act   = (char*)p;   p += (size_t)B * K1_PAD;                  // fp8 A-input
    char*  A1    = act;                                                  // aliases (dead after GEMM1)
    char*  Wt_in = p;  p += (size_t)H_DIM * K1_PAD;
    char*  Wt_r1 = p;  p += (size_t)H_DIM * H_DIM;
    char*  Wt_r2 = p;  p += (size_t)H_DIM * H_DIM;
    char*  Wt_f  = p;  p += (size_t)P_DIM * H_DIM;

    // 1) prep: L2 norms + fp8 concat A1 (x16, K-interleaved, single read)
    prep_a1<<<B, 256, 0, stream>>>(x1, x2, gf, A1);

    // 2) all weight transposes+cvt (x16, K-interleaved) in one launch
    transpose_cvt_all<<<dim3(K1_PAD / 64, H_DIM / 64, 4), 256, 0, stream>>>(
        W_in, Wt_in, W_r1, Wt_r1, W_r2, Wt_r2, W_f, Wt_f);

    // 3) input_proj GEMM (8-phase 256^2) + LN -> act fp8 + residual bf16
    gemm256_f8<K1_PAD><<<dim3(B / 256, H_DIM / 256), 512, 0, stream>>>(
        A1, Wt_in, b_in, INV_G1, preb, H_DIM);
    ln_relu_f8<0, 1><<<B / 4, 256, 0, stream>>>(preb, g_in, be_in, nullptr, act, fb);

    // 4) residual block 1
    gemm256_f8<H_DIM><<<dim3(B / 256, H_DIM / 256), 512, 0, stream>>>(
        act, Wt_r1, b_r1, INV_G, preb, H_DIM);
    ln_relu_f8<1, 1><<<B / 4, 256, 0, stream>>>(preb, g_r1, be_r1, fb, act, fb);

    // 5) residual block 2 (no bf16 residual needed after this)
    gemm256_f8<H_DIM><<<dim3(B / 256, H_DIM / 256), 512, 0, stream>>>(
        act, Wt_r2, b_r2, INV_G, preb, H_DIM);
    ln_relu_f8<1, 0><<<B / 4, 256, 0, stream>>>(preb, g_r2, be_r2, fb, act, nullptr);

    // 6) final_proj (N=256, bf16 out, legacy 2-wave tile -> grid 256 = 1/CU)
    gemm_f8<2, H_DIM><<<dim3(B / 128, P_DIM / 128), 256, 0, stream>>>(
        act, Wt_f, b_f, INV_G, preb, P_DIM);

    // 7) fused final LN + classifier + gender mask (wave per row)
    ln_cls<<<B / 4, 256, 0, stream>>>(preb, g_f, be_f, W_c, b_c, gf, out);
}